// Round 3
// baseline (2164.105 us; speedup 1.0000x reference)
//
#include <hip/hip_runtime.h>
#include <hip/hip_bf16.h>
#include <stdint.h>

#define B_Q     2
#define N_TOK   131072        // 128*128*8
#define S_VAL   9507          // 7191 + 1848 + 468
#define PROW    292           // P tile row stride (bf16 units), 288 cols used
#define TROW    36            // transpose tile row stride (f32)

typedef __attribute__((ext_vector_type(8))) short short8;
typedef __attribute__((ext_vector_type(4))) short short4v;
typedef __attribute__((ext_vector_type(4))) float f32x4;

__device__ __forceinline__ unsigned short f32_bf16(float f) {
    unsigned u = __float_as_uint(f);
    u += 0x7FFFu + ((u >> 16) & 1u);           // RNE
    return (unsigned short)(u >> 16);
}
__device__ __forceinline__ float bf16_f32(unsigned short h) {
    return __uint_as_float((unsigned)h << 16);
}

// ---------------------------------------------------------------------------
// K_aux: blocks [0,1024): voxel-mask scatter; blocks [1024,1234): weight pack.
// Pack layout: fragment element (nt,ks,lane,j) holds W[k][n],
//   n = nt*16 + (lane&15), k = ks*32 + (lane>>4)*8 + j.
// ---------------------------------------------------------------------------
__global__ __launch_bounds__(256) void aux_kernel(
    const int* __restrict__ vol, int* __restrict__ mask,
    const float* __restrict__ Woff, const float* __restrict__ boff,
    const float* __restrict__ Ww,   const float* __restrict__ bw,
    const float* __restrict__ Wo,
    unsigned short* __restrict__ wcatp, unsigned short* __restrict__ wop,
    float* __restrict__ bias288)
{
    int blk = blockIdx.x;
    int t   = threadIdx.x;
    if (blk < 1024) {
        int i = blk * 256 + t;
        int b = i >> 17;
        const int* p = vol + (size_t)i * 3;
        int x = p[0], y = p[1], z = p[2];
        if (x >= 0 && x < 128 && y >= 0 && y < 128 && z >= 0 && z < 8)
            mask[b * N_TOK + x * 1024 + y * 8 + z] = 1;
        return;
    }
    int idx = (blk - 1024) * 256 + t;
    if (idx < 36864) {
        int j = idx & 7, l = (idx >> 3) & 63, ks = (idx >> 9) & 3, nt = idx >> 11;
        int n = nt * 16 + (l & 15);
        int k = ks * 32 + (l >> 4) * 8 + j;
        float v = (n < 192) ? Woff[k * 192 + n] : Ww[k * 96 + (n - 192)];
        wcatp[idx] = f32_bf16(v);
    } else if (idx < 53248) {
        int i2 = idx - 36864;
        int j = i2 & 7, l = (i2 >> 3) & 63, ks = (i2 >> 9) & 3, nt = i2 >> 11;
        int n = nt * 16 + (l & 15);
        int k = ks * 32 + (l >> 4) * 8 + j;
        wop[i2] = f32_bf16(Wo[k * 128 + n]);
    } else if (idx < 53536) {
        int i2 = idx - 53248;
        bias288[i2] = (i2 < 192) ? boff[i2] : bw[i2 - 192];
    }
}

// ---------------------------------------------------------------------------
// K1: value projection -> bf16 value table, HEAD-MAJOR: [b][h][s][16ch]
// 32 s-rows x 128 cols per block, 596 blocks.
// ---------------------------------------------------------------------------
__global__ __launch_bounds__(256) void value_proj_kernel(
    const float* __restrict__ f0, const float* __restrict__ f1,
    const float* __restrict__ f2,
    const float* __restrict__ Wv, const float* __restrict__ bv,
    unsigned short* __restrict__ value)
{
    __shared__ float Ast[128 * 36];   // A^T tile: [k][j], stride 36

    int blk = blockIdx.x;
    int b   = blk / 298;
    int s0  = (blk % 298) * 32;
    int t   = threadIdx.x;

    int j = t & 31;
    int a = t >> 5;
    int s = s0 + j;
    #pragma unroll
    for (int i = 0; i < 16; ++i) {
        int k = a + 8 * i;
        float v = 0.f;
        if (s < S_VAL) {
            if (s < 7191)      v = f0[((size_t)b * 128 + k) * 7191 + s];
            else if (s < 9039) v = f1[((size_t)b * 128 + k) * 1848 + (s - 7191)];
            else               v = f2[((size_t)b * 128 + k) * 468  + (s - 9039)];
        }
        Ast[k * 36 + j] = v;
    }
    __syncthreads();

    int c  = t & 127;
    int rg = t >> 7;                  // 0/1 -> rows rg*16 .. rg*16+15
    float acc[16];
    #pragma unroll
    for (int i = 0; i < 16; ++i) acc[i] = 0.f;

    for (int k = 0; k < 128; ++k) {
        float wv = Wv[k * 128 + c];
        const float4* arow = (const float4*)&Ast[k * 36 + rg * 16];
        #pragma unroll
        for (int ii = 0; ii < 4; ++ii) {
            float4 av = arow[ii];
            acc[4 * ii + 0] += av.x * wv;
            acc[4 * ii + 1] += av.y * wv;
            acc[4 * ii + 2] += av.z * wv;
            acc[4 * ii + 3] += av.w * wv;
        }
    }
    float bvc = bv[c];
    int h = c >> 4, ch = c & 15;
    #pragma unroll
    for (int i = 0; i < 16; ++i) {
        int s2 = s0 + rg * 16 + i;
        if (s2 < S_VAL)
            value[((size_t)(b * 8 + h) * S_VAL + s2) * 16 + ch] = f32_bf16(acc[i] + bvc);
    }
}

// ---------------------------------------------------------------------------
// K2 mega-kernel (MFMA). 32 tokens/block, 256 threads.
// ---------------------------------------------------------------------------
__global__ __launch_bounds__(256, 5) void fused_kernel(
    const float* __restrict__ embed, const float* __restrict__ pos,
    const float* __restrict__ refpix,
    const unsigned short* __restrict__ wcatp,
    const unsigned short* __restrict__ wop,
    const float* __restrict__ bias288,
    const float* __restrict__ bo,
    const float* __restrict__ ln_g, const float* __restrict__ ln_b,
    const unsigned short* __restrict__ value,
    const int* __restrict__ mask,
    float* __restrict__ out)
{
    __shared__ short qA[4096];                       // 8 KB: q A-frags, then acc A-frags
    __shared__ __align__(16) char r2[32 * PROW * 2]; // 18688 B: P (bf16) / transpose (f32)

    unsigned short* Pb  = (unsigned short*)r2;
    float*          u2t = (float*)r2;                // 128 x TROW f32
    short8*         qA8 = (short8*)qA;

    int t     = threadIdx.x;
    int bb    = blockIdx.x;
    int b     = bb >> 12;
    int tbase = (bb & 4095) * 32;
    int lane  = t & 63;
    int wvid  = t >> 6;

    // ---------------- Ph1: q -> bf16 A-frags ----------------
    {
        const float4* e4 = (const float4*)(embed + ((size_t)b * N_TOK + tbase) * 128);
        const float4* p4 = (const float4*)(pos   + ((size_t)b * N_TOK + tbase) * 128);
        #pragma unroll
        for (int i = 0; i < 4; ++i) {
            int idx = t + 256 * i;             // 0..1023 float4s
            int r = idx >> 5, k4 = idx & 31;
            float4 e = e4[idx];
            float4 p = p4[idx];
            short4v q;
            q.x = (short)f32_bf16(e.x + p.x);
            q.y = (short)f32_bf16(e.y + p.y);
            q.z = (short)f32_bf16(e.z + p.z);
            q.w = (short)f32_bf16(e.w + p.w);
            int kg = k4 >> 1;
            int mt = r >> 4, ks = kg >> 2;
            int lpos = (r & 15) + ((kg & 3) << 4);
            short4v* dst = (short4v*)((char*)qA +
                (((size_t)(mt * 4 + ks) * 64 + lpos) * 16 + (k4 & 1) * 8));
            *dst = q;
        }
    }
    __syncthreads();

    // ---------------- Ph2: P = q @ [Woff|Ww] (MFMA) ----------------
    {
        int mt = wvid & 1;
        int n0 = (wvid >> 1) * 9;
        f32x4 acc[9];
        #pragma unroll
        for (int i = 0; i < 9; ++i) acc[i] = (f32x4)(0.f);
        const short8* bp = (const short8*)wcatp;
        #pragma unroll
        for (int ks = 0; ks < 4; ++ks) {
            short8 af = qA8[(mt * 4 + ks) * 64 + lane];
            #pragma unroll
            for (int i = 0; i < 9; ++i) {
                short8 bf = bp[((n0 + i) * 4 + ks) * 64 + lane];
                acc[i] = __builtin_amdgcn_mfma_f32_16x16x32_bf16(af, bf, acc[i], 0, 0, 0);
            }
        }
        int col = lane & 15, quad = lane >> 4;
        #pragma unroll
        for (int i = 0; i < 9; ++i) {
            int n = (n0 + i) * 16 + col;
            float bsv = bias288[n];
            #pragma unroll
            for (int reg = 0; reg < 4; ++reg) {
                int row = mt * 16 + quad * 4 + reg;
                Pb[row * PROW + n] = f32_bf16(acc[i][reg] + bsv);
            }
        }
    }
    __syncthreads();

    // ---------------- Ph3: softmax (registers) + bilinear gather ----------------
    {
        int r = t >> 3, h = t & 7;
        int n = tbase + r;
        float2 rp = ((const float2*)refpix)[(size_t)b * N_TOK + n];
        const unsigned short* pr = &Pb[r * PROW];

        // vector LDS reads: 24 offsets + 12 logits per (token, head)
        uint2 ofs2[6], lg2[3];
        #pragma unroll
        for (int i = 0; i < 6; ++i)
            ofs2[i] = *(const uint2*)(pr + h * 24 + i * 4);
        #pragma unroll
        for (int i = 0; i < 3; ++i)
            lg2[i] = *(const uint2*)(pr + 192 + h * 12 + i * 4);
        const unsigned short* ofs = (const unsigned short*)ofs2;
        const unsigned short* lg  = (const unsigned short*)lg2;

        float wgt[12];
        float mx = -1e30f;
        #pragma unroll
        for (int i = 0; i < 12; ++i) { wgt[i] = bf16_f32(lg[i]); mx = fmaxf(mx, wgt[i]); }
        float ssum = 0.f;
        #pragma unroll
        for (int i = 0; i < 12; ++i) { wgt[i] = __expf(wgt[i] - mx); ssum += wgt[i]; }
        float sinv = 1.f / ssum;

        float acc16[16];
        #pragma unroll
        for (int i = 0; i < 16; ++i) acc16[i] = 0.f;

        const int LH[3] = {47, 24, 12};
        const int LW[3] = {153, 77, 39};
        const int LS[3] = {0, 7191, 9039};

        #pragma unroll
        for (int l = 0; l < 3; ++l) {
            const int w  = LW[l];
            const int hh = LH[l];
            float bx = rp.x * (float)w  - 0.5f;
            float by = rp.y * (float)hh - 0.5f;
            const unsigned short* vb = value + ((size_t)(b * 8 + h) * S_VAL + LS[l]) * 16;
            #pragma unroll
            for (int p = 0; p < 4; ++p) {
                float ox = bf16_f32(ofs[(l * 4 + p) * 2 + 0]);
                float oy = bf16_f32(ofs[(l * 4 + p) * 2 + 1]);
                float aw = wgt[l * 4 + p] * sinv;
                float x = bx + ox;
                float y = by + oy;
                float x0f = floorf(x), y0f = floorf(y);
                float fx = x - x0f, fy = y - y0f;
                int x0 = (int)x0f, y0 = (int)y0f;
                int x1 = x0 + 1,   y1 = y0 + 1;
                // clamped indices -> UNCONDITIONAL loads; OOB handled via zero weights
                int xc0 = min(max(x0, 0), w - 1),  xc1 = min(max(x1, 0), w - 1);
                int yc0 = min(max(y0, 0), hh - 1), yc1 = min(max(y1, 0), hh - 1);
                float wx0 = (x0 < 0 || x0 >= w)  ? 0.f : (1.f - fx);
                float wx1 = (x1 < 0 || x1 >= w)  ? 0.f : fx;
                float wy0 = (y0 < 0 || y0 >= hh) ? 0.f : (1.f - fy);
                float wy1 = (y1 < 0 || y1 >= hh) ? 0.f : fy;
                float w00 = wx0 * wy0 * aw, w01 = wx1 * wy0 * aw;
                float w10 = wx0 * wy1 * aw, w11 = wx1 * wy1 * aw;
                const uint4* t00 = (const uint4*)(vb + (size_t)(yc0 * w + xc0) * 16);
                const uint4* t01 = (const uint4*)(vb + (size_t)(yc0 * w + xc1) * 16);
                const uint4* t10 = (const uint4*)(vb + (size_t)(yc1 * w + xc0) * 16);
                const uint4* t11 = (const uint4*)(vb + (size_t)(yc1 * w + xc1) * 16);
                uint4 a0 = t00[0], a1 = t00[1];
                uint4 b0 = t01[0], b1 = t01[1];
                uint4 c0 = t10[0], c1 = t10[1];
                uint4 d0 = t11[0], d1 = t11[1];
#define ACC2(u, cw, i0) do { \
    acc16[i0]     = fmaf(__uint_as_float((u) << 16),         cw, acc16[i0]); \
    acc16[i0 + 1] = fmaf(__uint_as_float((u) & 0xffff0000u), cw, acc16[i0 + 1]); } while (0)
                ACC2(a0.x, w00, 0); ACC2(a0.y, w00, 2); ACC2(a0.z, w00, 4); ACC2(a0.w, w00, 6);
                ACC2(a1.x, w00, 8); ACC2(a1.y, w00,10); ACC2(a1.z, w00,12); ACC2(a1.w, w00,14);
                ACC2(b0.x, w01, 0); ACC2(b0.y, w01, 2); ACC2(b0.z, w01, 4); ACC2(b0.w, w01, 6);
                ACC2(b1.x, w01, 8); ACC2(b1.y, w01,10); ACC2(b1.z, w01,12); ACC2(b1.w, w01,14);
                ACC2(c0.x, w10, 0); ACC2(c0.y, w10, 2); ACC2(c0.z, w10, 4); ACC2(c0.w, w10, 6);
                ACC2(c1.x, w10, 8); ACC2(c1.y, w10,10); ACC2(c1.z, w10,12); ACC2(c1.w, w10,14);
                ACC2(d0.x, w11, 0); ACC2(d0.y, w11, 2); ACC2(d0.z, w11, 4); ACC2(d0.w, w11, 6);
                ACC2(d1.x, w11, 8); ACC2(d1.y, w11,10); ACC2(d1.z, w11,12); ACC2(d1.w, w11,14);
#undef ACC2
            }
        }
        // store acc as bf16 A-frags into qA region
        short8 v0, v1;
        #pragma unroll
        for (int j2 = 0; j2 < 8; ++j2) {
            v0[j2] = (short)f32_bf16(acc16[j2]);
            v1[j2] = (short)f32_bf16(acc16[8 + j2]);
        }
        int mt = r >> 4, rl = r & 15;
        int kg0 = 2 * h, kg1 = 2 * h + 1;
        qA8[(mt * 4 + (kg0 >> 2)) * 64 + rl + ((kg0 & 3) << 4)] = v0;
        qA8[(mt * 4 + (kg1 >> 2)) * 64 + rl + ((kg1 & 3) << 4)] = v1;
    }
    __syncthreads();

    // ---------------- Ph4: acc @ Wo + bo (MFMA) -> transpose tile ----------------
    {
        int mt  = wvid & 1;
        int nt0 = (wvid >> 1) * 4;
        f32x4 acc[4];
        #pragma unroll
        for (int i = 0; i < 4; ++i) acc[i] = (f32x4)(0.f);
        const short8* bp = (const short8*)wop;
        #pragma unroll
        for (int ks = 0; ks < 4; ++ks) {
            short8 af = qA8[(mt * 4 + ks) * 64 + lane];
            #pragma unroll
            for (int i = 0; i < 4; ++i) {
                short8 bf = bp[((nt0 + i) * 4 + ks) * 64 + lane];
                acc[i] = __builtin_amdgcn_mfma_f32_16x16x32_bf16(af, bf, acc[i], 0, 0, 0);
            }
        }
        int col = lane & 15, quad = lane >> 4;
        #pragma unroll
        for (int i = 0; i < 4; ++i) {
            int c = (nt0 + i) * 16 + col;
            float bc = bo[c];
            #pragma unroll
            for (int reg = 0; reg < 4; ++reg) {
                int row = mt * 16 + quad * 4 + reg;
                u2t[c * TROW + row] = acc[i][reg] + bc;
            }
        }
    }
    __syncthreads();

    // ---------------- Ph4b: residual + LayerNorm + mask ----------------
    {
        int r = t >> 3, j = t & 7;
        int n = tbase + r;
        const float* eb = embed + ((size_t)b * N_TOK + n) * 128;
        float v[16], ev[16];
        float s1 = 0.f, s2 = 0.f;
        #pragma unroll
        for (int i = 0; i < 16; ++i) {
            int c = j + 8 * i;
            float e = eb[c];
            float x = u2t[c * TROW + r] + e;
            ev[i] = e; v[i] = x;
            s1 += x; s2 += x * x;
        }
        #pragma unroll
        for (int m = 1; m < 8; m <<= 1) {
            s1 += __shfl_xor(s1, m, 64);
            s2 += __shfl_xor(s2, m, 64);
        }
        float mu   = s1 * (1.f / 128.f);
        float var  = s2 * (1.f / 128.f) - mu * mu;
        float rstd = rsqrtf(var + 1e-5f);
        int   msk  = mask[(size_t)b * N_TOK + n];
        #pragma unroll
        for (int i = 0; i < 16; ++i) {
            int c = j + 8 * i;
            float yv = (v[i] - mu) * rstd * ln_g[c] + ln_b[c];
            u2t[c * TROW + r] = msk ? yv : ev[i];
        }
    }
    __syncthreads();

    // ---------------- Ph5: coalesced float4 store to (B, C, N) ----------------
    {
        #pragma unroll
        for (int i = 0; i < 4; ++i) {
            int idx = t + 256 * i;
            int c = idx >> 3, r4 = idx & 7;
            float4 vv = *(const float4*)&u2t[c * TROW + r4 * 4];
            *(float4*)&out[((size_t)(b * 128 + c)) * N_TOK + tbase + r4 * 4] = vv;
        }
    }
}

// ---------------------------------------------------------------------------
extern "C" void kernel_launch(void* const* d_in, const int* in_sizes, int n_in,
                              void* d_out, int out_size, void* d_ws, size_t ws_size,
                              hipStream_t stream)
{
    (void)n_in; (void)out_size; (void)ws_size;

    const float* embed = (const float*)d_in[0];
    const float* posp  = (const float*)d_in[1];
    const int*   vol   = (const int*)  d_in[2];
    const float* refp  = (const float*)d_in[3];

    int iW, iF;
    if (in_sizes[4] == 128 * 128) { iW = 4; iF = 14; }   // dict order
    else                          { iF = 4; iW = 7;  }   // signature order

    const float* Wv   = (const float*)d_in[iW + 0];
    const float* bv   = (const float*)d_in[iW + 1];
    const float* Woff = (const float*)d_in[iW + 2];
    const float* boff = (const float*)d_in[iW + 3];
    const float* Ww   = (const float*)d_in[iW + 4];
    const float* bw   = (const float*)d_in[iW + 5];
    const float* Wo   = (const float*)d_in[iW + 6];
    const float* bo   = (const float*)d_in[iW + 7];
    const float* lng  = (const float*)d_in[iW + 8];
    const float* lnb  = (const float*)d_in[iW + 9];
    const float* f0   = (const float*)d_in[iF + 0];
    const float* f1   = (const float*)d_in[iF + 1];
    const float* f2   = (const float*)d_in[iF + 2];

    char* ws = (char*)d_ws;
    int*            maskbuf = (int*)ws;                                   // 1 MB
    unsigned short* value   = (unsigned short*)(ws + 1048576);            // 4.87 MB
    unsigned short* wcatp   = (unsigned short*)(ws + 1048576 + 4867584);  // 73728 B
    unsigned short* wop     = (unsigned short*)(ws + 1048576 + 4867584 + 73728); // 32768 B
    float*          bias288 = (float*)(ws + 1048576 + 4867584 + 73728 + 32768); // 1152 B

    hipMemsetAsync(maskbuf, 0, (size_t)B_Q * N_TOK * sizeof(int), stream);
    aux_kernel<<<1234, 256, 0, stream>>>(vol, maskbuf, Woff, boff, Ww, bw, Wo,
                                         wcatp, wop, bias288);
    value_proj_kernel<<<B_Q * 298, 256, 0, stream>>>(f0, f1, f2, Wv, bv, value);
    fused_kernel<<<B_Q * 4096, 256, 0, stream>>>(
        embed, posp, refp, wcatp, wop, bias288, bo, lng, lnb,
        value, maskbuf, (float*)d_out);
}

// Round 4
// 1676.593 us; speedup vs baseline: 1.2908x; 1.2908x over previous
//
#include <hip/hip_runtime.h>
#include <hip/hip_bf16.h>
#include <stdint.h>

#define B_Q     2
#define N_TOK   131072        // 128*128*8
#define S_VAL   9507          // 7191 + 1848 + 468
#define PROW    292           // P tile row stride (bf16 units), 288 cols used
#define TROW    36            // transpose tile row stride (f32)

typedef __attribute__((ext_vector_type(8))) short short8;
typedef __attribute__((ext_vector_type(4))) short short4v;
typedef __attribute__((ext_vector_type(4))) float f32x4;

__device__ __forceinline__ unsigned short f32_bf16(float f) {
    unsigned u = __float_as_uint(f);
    u += 0x7FFFu + ((u >> 16) & 1u);           // RNE
    return (unsigned short)(u >> 16);
}
__device__ __forceinline__ float bf16_f32(unsigned short h) {
    return __uint_as_float((unsigned)h << 16);
}

// ---------------------------------------------------------------------------
// K_aux: blocks [0,1024): voxel-mask scatter; blocks [1024,1234): weight pack.
// Pack layout: fragment element (nt,ks,lane,j) holds W[k][n],
//   n = nt*16 + (lane&15), k = ks*32 + (lane>>4)*8 + j.
// ---------------------------------------------------------------------------
__global__ __launch_bounds__(256) void aux_kernel(
    const int* __restrict__ vol, int* __restrict__ mask,
    const float* __restrict__ Woff, const float* __restrict__ boff,
    const float* __restrict__ Ww,   const float* __restrict__ bw,
    const float* __restrict__ Wo,
    unsigned short* __restrict__ wcatp, unsigned short* __restrict__ wop,
    float* __restrict__ bias288)
{
    int blk = blockIdx.x;
    int t   = threadIdx.x;
    if (blk < 1024) {
        int i = blk * 256 + t;
        int b = i >> 17;
        const int* p = vol + (size_t)i * 3;
        int x = p[0], y = p[1], z = p[2];
        if (x >= 0 && x < 128 && y >= 0 && y < 128 && z >= 0 && z < 8)
            mask[b * N_TOK + x * 1024 + y * 8 + z] = 1;
        return;
    }
    int idx = (blk - 1024) * 256 + t;
    if (idx < 36864) {
        int j = idx & 7, l = (idx >> 3) & 63, ks = (idx >> 9) & 3, nt = idx >> 11;
        int n = nt * 16 + (l & 15);
        int k = ks * 32 + (l >> 4) * 8 + j;
        float v = (n < 192) ? Woff[k * 192 + n] : Ww[k * 96 + (n - 192)];
        wcatp[idx] = f32_bf16(v);
    } else if (idx < 53248) {
        int i2 = idx - 36864;
        int j = i2 & 7, l = (i2 >> 3) & 63, ks = (i2 >> 9) & 3, nt = i2 >> 11;
        int n = nt * 16 + (l & 15);
        int k = ks * 32 + (l >> 4) * 8 + j;
        wop[i2] = f32_bf16(Wo[k * 128 + n]);
    } else if (idx < 53536) {
        int i2 = idx - 53248;
        bias288[i2] = (i2 < 192) ? boff[i2] : bw[i2 - 192];
    }
}

// ---------------------------------------------------------------------------
// K1: value projection -> bf16 value table, HEAD-MAJOR: [b][h][s][16ch]
// 32 s-rows x 128 cols per block, 596 blocks.
// ---------------------------------------------------------------------------
__global__ __launch_bounds__(256) void value_proj_kernel(
    const float* __restrict__ f0, const float* __restrict__ f1,
    const float* __restrict__ f2,
    const float* __restrict__ Wv, const float* __restrict__ bv,
    unsigned short* __restrict__ value)
{
    __shared__ float Ast[128 * 36];   // A^T tile: [k][j], stride 36

    int blk = blockIdx.x;
    int b   = blk / 298;
    int s0  = (blk % 298) * 32;
    int t   = threadIdx.x;

    int j = t & 31;
    int a = t >> 5;
    int s = s0 + j;
    #pragma unroll
    for (int i = 0; i < 16; ++i) {
        int k = a + 8 * i;
        float v = 0.f;
        if (s < S_VAL) {
            if (s < 7191)      v = f0[((size_t)b * 128 + k) * 7191 + s];
            else if (s < 9039) v = f1[((size_t)b * 128 + k) * 1848 + (s - 7191)];
            else               v = f2[((size_t)b * 128 + k) * 468  + (s - 9039)];
        }
        Ast[k * 36 + j] = v;
    }
    __syncthreads();

    int c  = t & 127;
    int rg = t >> 7;                  // 0/1 -> rows rg*16 .. rg*16+15
    float acc[16];
    #pragma unroll
    for (int i = 0; i < 16; ++i) acc[i] = 0.f;

    for (int k = 0; k < 128; ++k) {
        float wv = Wv[k * 128 + c];
        const float4* arow = (const float4*)&Ast[k * 36 + rg * 16];
        #pragma unroll
        for (int ii = 0; ii < 4; ++ii) {
            float4 av = arow[ii];
            acc[4 * ii + 0] += av.x * wv;
            acc[4 * ii + 1] += av.y * wv;
            acc[4 * ii + 2] += av.z * wv;
            acc[4 * ii + 3] += av.w * wv;
        }
    }
    float bvc = bv[c];
    int h = c >> 4, ch = c & 15;
    #pragma unroll
    for (int i = 0; i < 16; ++i) {
        int s2 = s0 + rg * 16 + i;
        if (s2 < S_VAL)
            value[((size_t)(b * 8 + h) * S_VAL + s2) * 16 + ch] = f32_bf16(acc[i] + bvc);
    }
}

// ---------------------------------------------------------------------------
// K2 mega-kernel (MFMA). 32 tokens/block, 256 threads.
// launch_bounds(256,4): VGPR cap 128 so the branchless 8-wide gather batches
// stay in registers (R3's (256,5)=102 cap caused scratch spill -> 7 GB traffic).
// ---------------------------------------------------------------------------
__global__ __launch_bounds__(256, 4) void fused_kernel(
    const float* __restrict__ embed, const float* __restrict__ pos,
    const float* __restrict__ refpix,
    const unsigned short* __restrict__ wcatp,
    const unsigned short* __restrict__ wop,
    const float* __restrict__ bias288,
    const float* __restrict__ bo,
    const float* __restrict__ ln_g, const float* __restrict__ ln_b,
    const unsigned short* __restrict__ value,
    const int* __restrict__ mask,
    float* __restrict__ out)
{
    __shared__ short qA[4096];                       // 8 KB: q A-frags, then acc A-frags
    __shared__ __align__(16) char r2[32 * PROW * 2]; // 18688 B: P (bf16) / transpose (f32)

    unsigned short* Pb  = (unsigned short*)r2;
    float*          u2t = (float*)r2;                // 128 x TROW f32
    short8*         qA8 = (short8*)qA;

    int t     = threadIdx.x;
    int bb    = blockIdx.x;
    int b     = bb >> 12;
    int tbase = (bb & 4095) * 32;
    int lane  = t & 63;
    int wvid  = t >> 6;

    // ---------------- Ph1: q -> bf16 A-frags ----------------
    {
        const float4* e4 = (const float4*)(embed + ((size_t)b * N_TOK + tbase) * 128);
        const float4* p4 = (const float4*)(pos   + ((size_t)b * N_TOK + tbase) * 128);
        #pragma unroll
        for (int i = 0; i < 4; ++i) {
            int idx = t + 256 * i;             // 0..1023 float4s
            int r = idx >> 5, k4 = idx & 31;
            float4 e = e4[idx];
            float4 p = p4[idx];
            short4v q;
            q.x = (short)f32_bf16(e.x + p.x);
            q.y = (short)f32_bf16(e.y + p.y);
            q.z = (short)f32_bf16(e.z + p.z);
            q.w = (short)f32_bf16(e.w + p.w);
            int kg = k4 >> 1;
            int mt = r >> 4, ks = kg >> 2;
            int lpos = (r & 15) + ((kg & 3) << 4);
            short4v* dst = (short4v*)((char*)qA +
                (((size_t)(mt * 4 + ks) * 64 + lpos) * 16 + (k4 & 1) * 8));
            *dst = q;
        }
    }
    __syncthreads();

    // ---------------- Ph2: P = q @ [Woff|Ww] (MFMA) ----------------
    {
        int mt = wvid & 1;
        int n0 = (wvid >> 1) * 9;
        f32x4 acc[9];
        #pragma unroll
        for (int i = 0; i < 9; ++i) acc[i] = (f32x4)(0.f);
        const short8* bp = (const short8*)wcatp;
        #pragma unroll
        for (int ks = 0; ks < 4; ++ks) {
            short8 af = qA8[(mt * 4 + ks) * 64 + lane];
            #pragma unroll
            for (int i = 0; i < 9; ++i) {
                short8 bf = bp[((n0 + i) * 4 + ks) * 64 + lane];
                acc[i] = __builtin_amdgcn_mfma_f32_16x16x32_bf16(af, bf, acc[i], 0, 0, 0);
            }
        }
        int col = lane & 15, quad = lane >> 4;
        #pragma unroll
        for (int i = 0; i < 9; ++i) {
            int n = (n0 + i) * 16 + col;
            float bsv = bias288[n];
            #pragma unroll
            for (int reg = 0; reg < 4; ++reg) {
                int row = mt * 16 + quad * 4 + reg;
                Pb[row * PROW + n] = f32_bf16(acc[i][reg] + bsv);
            }
        }
    }
    __syncthreads();

    // ---------------- Ph2b: softmax (head, 12), LDS in-place ----------------
    {
        int r = t >> 3, h = t & 7;
        unsigned short* pw = &Pb[r * PROW + 192 + h * 12];
        float e[12];
        #pragma unroll
        for (int i = 0; i < 12; ++i) e[i] = bf16_f32(pw[i]);
        float mx = e[0];
        #pragma unroll
        for (int i = 1; i < 12; ++i) mx = fmaxf(mx, e[i]);
        float ssum = 0.f;
        #pragma unroll
        for (int i = 0; i < 12; ++i) { e[i] = __expf(e[i] - mx); ssum += e[i]; }
        float inv = 1.f / ssum;
        #pragma unroll
        for (int i = 0; i < 12; ++i) pw[i] = f32_bf16(e[i] * inv);
    }
    // no barrier: Ph3 thread (r,h) reads exactly what it wrote

    // ---------------- Ph3: bilinear gather (branchless taps) ----------------
    {
        int r = t >> 3, h = t & 7;
        int n = tbase + r;
        float2 rp = ((const float2*)refpix)[(size_t)b * N_TOK + n];
        const unsigned short* pr = &Pb[r * PROW];

        float acc16[16];
        #pragma unroll
        for (int i = 0; i < 16; ++i) acc16[i] = 0.f;

        const int LH[3] = {47, 24, 12};
        const int LW[3] = {153, 77, 39};
        const int LS[3] = {0, 7191, 9039};

        #pragma unroll
        for (int l = 0; l < 3; ++l) {
            const int w  = LW[l];
            const int hh = LH[l];
            float bx = rp.x * (float)w  - 0.5f;   // ref*w + off - 0.5
            float by = rp.y * (float)hh - 0.5f;
            const unsigned short* vb = value + ((size_t)(b * 8 + h) * S_VAL + LS[l]) * 16;
            #pragma unroll
            for (int p = 0; p < 4; ++p) {
                float ox = bf16_f32(pr[((h * 3 + l) * 4 + p) * 2 + 0]);
                float oy = bf16_f32(pr[((h * 3 + l) * 4 + p) * 2 + 1]);
                float aw = bf16_f32(pr[192 + h * 12 + l * 4 + p]);
                float x = bx + ox;
                float y = by + oy;
                float x0f = floorf(x), y0f = floorf(y);
                float fx = x - x0f, fy = y - y0f;
                int x0 = (int)x0f, y0 = (int)y0f;
                int x1 = x0 + 1,   y1 = y0 + 1;
                // clamped indices -> unconditional loads; OOB -> zero weights
                int xc0 = min(max(x0, 0), w - 1),  xc1 = min(max(x1, 0), w - 1);
                int yc0 = min(max(y0, 0), hh - 1), yc1 = min(max(y1, 0), hh - 1);
                float wx0 = (x0 < 0 || x0 >= w)  ? 0.f : (1.f - fx);
                float wx1 = (x1 < 0 || x1 >= w)  ? 0.f : fx;
                float wy0 = (y0 < 0 || y0 >= hh) ? 0.f : (1.f - fy);
                float wy1 = (y1 < 0 || y1 >= hh) ? 0.f : fy;
                float w00 = wx0 * wy0 * aw, w01 = wx1 * wy0 * aw;
                float w10 = wx0 * wy1 * aw, w11 = wx1 * wy1 * aw;
                const uint4* t00 = (const uint4*)(vb + (size_t)(yc0 * w + xc0) * 16);
                const uint4* t01 = (const uint4*)(vb + (size_t)(yc0 * w + xc1) * 16);
                const uint4* t10 = (const uint4*)(vb + (size_t)(yc1 * w + xc0) * 16);
                const uint4* t11 = (const uint4*)(vb + (size_t)(yc1 * w + xc1) * 16);
                uint4 a0 = t00[0], a1 = t00[1];
                uint4 b0 = t01[0], b1 = t01[1];
                uint4 c0 = t10[0], c1 = t10[1];
                uint4 d0 = t11[0], d1 = t11[1];
#define ACC2(u, cw, i0) do { \
    acc16[i0]     = fmaf(__uint_as_float((u) << 16),         cw, acc16[i0]); \
    acc16[i0 + 1] = fmaf(__uint_as_float((u) & 0xffff0000u), cw, acc16[i0 + 1]); } while (0)
                ACC2(a0.x, w00, 0); ACC2(a0.y, w00, 2); ACC2(a0.z, w00, 4); ACC2(a0.w, w00, 6);
                ACC2(a1.x, w00, 8); ACC2(a1.y, w00,10); ACC2(a1.z, w00,12); ACC2(a1.w, w00,14);
                ACC2(b0.x, w01, 0); ACC2(b0.y, w01, 2); ACC2(b0.z, w01, 4); ACC2(b0.w, w01, 6);
                ACC2(b1.x, w01, 8); ACC2(b1.y, w01,10); ACC2(b1.z, w01,12); ACC2(b1.w, w01,14);
                ACC2(c0.x, w10, 0); ACC2(c0.y, w10, 2); ACC2(c0.z, w10, 4); ACC2(c0.w, w10, 6);
                ACC2(c1.x, w10, 8); ACC2(c1.y, w10,10); ACC2(c1.z, w10,12); ACC2(c1.w, w10,14);
                ACC2(d0.x, w11, 0); ACC2(d0.y, w11, 2); ACC2(d0.z, w11, 4); ACC2(d0.w, w11, 6);
                ACC2(d1.x, w11, 8); ACC2(d1.y, w11,10); ACC2(d1.z, w11,12); ACC2(d1.w, w11,14);
#undef ACC2
            }
        }
        // store acc as bf16 A-frags into qA region (q is dead)
        short8 v0, v1;
        #pragma unroll
        for (int j2 = 0; j2 < 8; ++j2) {
            v0[j2] = (short)f32_bf16(acc16[j2]);
            v1[j2] = (short)f32_bf16(acc16[8 + j2]);
        }
        int mt = r >> 4, rl = r & 15;
        int kg0 = 2 * h, kg1 = 2 * h + 1;
        qA8[(mt * 4 + (kg0 >> 2)) * 64 + rl + ((kg0 & 3) << 4)] = v0;
        qA8[(mt * 4 + (kg1 >> 2)) * 64 + rl + ((kg1 & 3) << 4)] = v1;
    }
    __syncthreads();

    // ---------------- Ph4: acc @ Wo + bo (MFMA) -> transpose tile ----------------
    {
        int mt  = wvid & 1;
        int nt0 = (wvid >> 1) * 4;
        f32x4 acc[4];
        #pragma unroll
        for (int i = 0; i < 4; ++i) acc[i] = (f32x4)(0.f);
        const short8* bp = (const short8*)wop;
        #pragma unroll
        for (int ks = 0; ks < 4; ++ks) {
            short8 af = qA8[(mt * 4 + ks) * 64 + lane];
            #pragma unroll
            for (int i = 0; i < 4; ++i) {
                short8 bf = bp[((nt0 + i) * 4 + ks) * 64 + lane];
                acc[i] = __builtin_amdgcn_mfma_f32_16x16x32_bf16(af, bf, acc[i], 0, 0, 0);
            }
        }
        int col = lane & 15, quad = lane >> 4;
        #pragma unroll
        for (int i = 0; i < 4; ++i) {
            int c = (nt0 + i) * 16 + col;
            float bc = bo[c];
            #pragma unroll
            for (int reg = 0; reg < 4; ++reg) {
                int row = mt * 16 + quad * 4 + reg;
                u2t[c * TROW + row] = acc[i][reg] + bc;
            }
        }
    }
    __syncthreads();

    // ---------------- Ph4b: residual + LayerNorm + mask ----------------
    {
        int r = t >> 3, j = t & 7;
        int n = tbase + r;
        const float* eb = embed + ((size_t)b * N_TOK + n) * 128;
        float v[16], ev[16];
        float s1 = 0.f, s2 = 0.f;
        #pragma unroll
        for (int i = 0; i < 16; ++i) {
            int c = j + 8 * i;
            float e = eb[c];
            float x = u2t[c * TROW + r] + e;
            ev[i] = e; v[i] = x;
            s1 += x; s2 += x * x;
        }
        #pragma unroll
        for (int m = 1; m < 8; m <<= 1) {
            s1 += __shfl_xor(s1, m, 64);
            s2 += __shfl_xor(s2, m, 64);
        }
        float mu   = s1 * (1.f / 128.f);
        float var  = s2 * (1.f / 128.f) - mu * mu;
        float rstd = rsqrtf(var + 1e-5f);
        int   msk  = mask[(size_t)b * N_TOK + n];
        #pragma unroll
        for (int i = 0; i < 16; ++i) {
            int c = j + 8 * i;
            float yv = (v[i] - mu) * rstd * ln_g[c] + ln_b[c];
            u2t[c * TROW + r] = msk ? yv : ev[i];
        }
    }
    __syncthreads();

    // ---------------- Ph5: coalesced float4 store to (B, C, N) ----------------
    {
        #pragma unroll
        for (int i = 0; i < 4; ++i) {
            int idx = t + 256 * i;
            int c = idx >> 3, r4 = idx & 7;
            float4 vv = *(const float4*)&u2t[c * TROW + r4 * 4];
            *(float4*)&out[((size_t)(b * 128 + c)) * N_TOK + tbase + r4 * 4] = vv;
        }
    }
}

// ---------------------------------------------------------------------------
extern "C" void kernel_launch(void* const* d_in, const int* in_sizes, int n_in,
                              void* d_out, int out_size, void* d_ws, size_t ws_size,
                              hipStream_t stream)
{
    (void)n_in; (void)out_size; (void)ws_size;

    const float* embed = (const float*)d_in[0];
    const float* posp  = (const float*)d_in[1];
    const int*   vol   = (const int*)  d_in[2];
    const float* refp  = (const float*)d_in[3];

    int iW, iF;
    if (in_sizes[4] == 128 * 128) { iW = 4; iF = 14; }   // dict order
    else                          { iF = 4; iW = 7;  }   // signature order

    const float* Wv   = (const float*)d_in[iW + 0];
    const float* bv   = (const float*)d_in[iW + 1];
    const float* Woff = (const float*)d_in[iW + 2];
    const float* boff = (const float*)d_in[iW + 3];
    const float* Ww   = (const float*)d_in[iW + 4];
    const float* bw   = (const float*)d_in[iW + 5];
    const float* Wo   = (const float*)d_in[iW + 6];
    const float* bo   = (const float*)d_in[iW + 7];
    const float* lng  = (const float*)d_in[iW + 8];
    const float* lnb  = (const float*)d_in[iW + 9];
    const float* f0   = (const float*)d_in[iF + 0];
    const float* f1   = (const float*)d_in[iF + 1];
    const float* f2   = (const float*)d_in[iF + 2];

    char* ws = (char*)d_ws;
    int*            maskbuf = (int*)ws;                                   // 1 MB
    unsigned short* value   = (unsigned short*)(ws + 1048576);            // 4.87 MB
    unsigned short* wcatp   = (unsigned short*)(ws + 1048576 + 4867584);  // 73728 B
    unsigned short* wop     = (unsigned short*)(ws + 1048576 + 4867584 + 73728); // 32768 B
    float*          bias288 = (float*)(ws + 1048576 + 4867584 + 73728 + 32768); // 1152 B

    hipMemsetAsync(maskbuf, 0, (size_t)B_Q * N_TOK * sizeof(int), stream);
    aux_kernel<<<1234, 256, 0, stream>>>(vol, maskbuf, Woff, boff, Ww, bw, Wo,
                                         wcatp, wop, bias288);
    value_proj_kernel<<<B_Q * 298, 256, 0, stream>>>(f0, f1, f2, Wv, bv, value);
    fused_kernel<<<B_Q * 4096, 256, 0, stream>>>(
        embed, posp, refp, wcatp, wop, bias288, bo, lng, lnb,
        value, maskbuf, (float*)d_out);
}